// Round 10
// baseline (235.051 us; speedup 1.0000x reference)
//
#include <hip/hip_runtime.h>
#include <hip/hip_bf16.h>
#include <math.h>

// Problem constants (fixed by the reference)
constexpr int Bb = 4;      // batch
constexpr int Cc = 256;    // channels
constexpr int Nn = 4096;   // sequence positions
constexpr int K  = 32;     // qk channels

constexpr float LOG2E = 1.4426950408889634f;
constexpr float C40L  = 40.0f * LOG2E;   // softmax shift, log2 domain

typedef __attribute__((ext_vector_type(8))) short short8;   // 8 x bf16
typedef __attribute__((ext_vector_type(4))) float f32x4;    // MFMA C/D
typedef __attribute__((ext_vector_type(2))) unsigned int uint2v;

static __device__ __forceinline__ unsigned int pack2(float a, float b) {
  union { __hip_bfloat162 h2; unsigned int u; } cv;
  cv.h2 = __float22bfloat162_rn(float2{a, b});
  return cv.u;
}
static __device__ __forceinline__ unsigned short f2bf(float f) {
  union { __hip_bfloat16 h; unsigned short u; } cv;
  cv.h = __float2bfloat16(f);
  return cv.u;
}
static __device__ __forceinline__ f32x4 MF(short8 a, short8 b, f32x4 c) {
  return __builtin_amdgcn_mfma_f32_16x16x32_bf16(a, b, c, 0, 0, 0);
}
static __device__ __forceinline__ float ex2(float v) {
  return __builtin_amdgcn_exp2f(v);
}
// async global->LDS, 16B per lane; LDS dest = wave-uniform base + lane*16
static __device__ __forceinline__ void stage16(const unsigned short* g,
                                               unsigned short* l) {
  __builtin_amdgcn_global_load_lds(
      (const __attribute__((address_space(1))) unsigned int*)g,
      (__attribute__((address_space(3))) unsigned int*)l, 16, 0, 0);
}

// ---------------------------------------------------------------------------
// TILED fragment layouts (primary path):
//   Etile[b][mt=m/16][no=n/8][ml=m&15][ne=n&7]  bf16   (B-operand order)
//   Htile[b][ct=c/16][no=n/8][cl=c&15][ne=n&7]  bf16   (A-operand order,
//         H'' = gamma*h/L folded)
// Element offset of n-position n0 within a tile-row: (n0/8)*128 = n0*16.
// ---------------------------------------------------------------------------

// ===== castW: Wh fp32 -> bf16 ==============================================
__global__ __launch_bounds__(256) void castW(
    const float* __restrict__ Wh, unsigned short* __restrict__ Whb)
{
  int i = (blockIdx.x * 256 + threadIdx.x) * 4;
  float4 v = *(const float4*)&Wh[i];
  uint2 o = { pack2(v.x, v.y), pack2(v.z, v.w) };
  *(uint2*)&Whb[i] = o;
}

// ===== castFG: Wf,Wg fp32 -> Wfgb bf16 =====================================
__global__ __launch_bounds__(256) void castFG(
    const float* __restrict__ Wf, const float* __restrict__ Wg,
    unsigned short* __restrict__ Wfgb)
{
  int g = (blockIdx.x * 256 + threadIdx.x) * 4;
  int row = g >> 8, c = g & 255;
  const float* src = (row < 32) ? &Wf[row*Cc + c] : &Wg[(row-32)*Cc + c];
  float4 v = *(const float4*)src;
  uint2 o = { pack2(v.x, v.y), pack2(v.z, v.w) };
  *(uint2*)&Wfgb[g] = o;
}

// ===== trans_k: xT[b][n][c] = bf16(x[b][c][n]) =============================
__global__ __launch_bounds__(256) void trans_k(
    const float* __restrict__ x, unsigned short* __restrict__ xT)
{
  __shared__ unsigned short Ls[64][65];
  const int b  = blockIdx.z;
  const int n0 = blockIdx.x * 64, c0 = blockIdx.y * 64;
  const int tid = threadIdx.x;
  {
    const int cr = tid >> 4, n4 = (tid & 15) * 4;
#pragma unroll
    for (int rr = 0; rr < 4; ++rr) {
      int c = rr * 16 + cr;
      float4 v = *(const float4*)&x[(size_t)(b*Cc + c0 + c)*Nn + n0 + n4];
      Ls[c][n4+0] = f2bf(v.x); Ls[c][n4+1] = f2bf(v.y);
      Ls[c][n4+2] = f2bf(v.z); Ls[c][n4+3] = f2bf(v.w);
    }
  }
  __syncthreads();
  {
    const int nw = tid >> 4, cw = (tid & 15) * 4;
#pragma unroll
    for (int rr = 0; rr < 4; ++rr) {
      int n = nw + rr * 16;
      unsigned int lo = (unsigned int)Ls[cw+0][n] | ((unsigned int)Ls[cw+1][n] << 16);
      unsigned int hi = (unsigned int)Ls[cw+2][n] | ((unsigned int)Ls[cw+3][n] << 16);
      uint2 o = { lo, hi };
      *(uint2*)&xT[(size_t)(b*Nn + n0 + n)*Cc + c0 + cw] = o;
    }
  }
}

// ===== proj_fgM: F' = LOG2E*(Wf x + bf), G = Wg x + bg via MFMA ============
__global__ __launch_bounds__(256) void proj_fgM(
    const unsigned short* __restrict__ xT, const unsigned short* __restrict__ Wfgb,
    const float* __restrict__ bf, const float* __restrict__ bg,
    unsigned short* __restrict__ Ft, unsigned short* __restrict__ Gt)
{
  const int b = blockIdx.y;
  const int tid = threadIdx.x, wave = tid >> 6, lane = tid & 63;
  const int q = lane >> 4, col = lane & 15;
  const int n = blockIdx.x * 64 + wave * 16 + col;

  const unsigned short* Bp = xT + (size_t)(b*Nn + n)*Cc + q*8;
  const f32x4 zero = {0.f,0.f,0.f,0.f};
  f32x4 af0 = zero, af1 = zero, ag0 = zero, ag1 = zero;
#pragma unroll
  for (int kc = 0; kc < 8; ++kc) {
    short8 bn = *(const short8*)(Bp + kc*32);
    short8 a0 = *(const short8*)(Wfgb + (size_t)( 0 + col)*Cc + kc*32 + q*8);
    short8 a1 = *(const short8*)(Wfgb + (size_t)(16 + col)*Cc + kc*32 + q*8);
    short8 a2 = *(const short8*)(Wfgb + (size_t)(32 + col)*Cc + kc*32 + q*8);
    short8 a3 = *(const short8*)(Wfgb + (size_t)(48 + col)*Cc + kc*32 + q*8);
    af0 = MF(a0, bn, af0); af1 = MF(a1, bn, af1);
    ag0 = MF(a2, bn, ag0); ag1 = MF(a3, bn, ag1);
  }
  float4 bf0 = *(const float4*)&bf[q*4],      bf1 = *(const float4*)&bf[16 + q*4];
  float4 bg0 = *(const float4*)&bg[q*4],      bg1 = *(const float4*)&bg[16 + q*4];
  uint2 F0 = { pack2((af0[0]+bf0.x)*LOG2E, (af0[1]+bf0.y)*LOG2E),
               pack2((af0[2]+bf0.z)*LOG2E, (af0[3]+bf0.w)*LOG2E) };
  uint2 F1 = { pack2((af1[0]+bf1.x)*LOG2E, (af1[1]+bf1.y)*LOG2E),
               pack2((af1[2]+bf1.z)*LOG2E, (af1[3]+bf1.w)*LOG2E) };
  uint2 G0 = { pack2(ag0[0]+bg0.x, ag0[1]+bg0.y), pack2(ag0[2]+bg0.z, ag0[3]+bg0.w) };
  uint2 G1 = { pack2(ag1[0]+bg1.x, ag1[1]+bg1.y), pack2(ag1[2]+bg1.z, ag1[3]+bg1.w) };
  unsigned short* fo = Ft + (size_t)(b*Nn + n)*K;
  unsigned short* go = Gt + (size_t)(b*Nn + n)*K;
  *(uint2*)(fo + q*4) = F0;  *(uint2*)(fo + 16 + q*4) = F1;
  *(uint2*)(go + q*4) = G0;  *(uint2*)(go + 16 + q*4) = G1;
}

// ===== pass1: Etile = exp2(S'-C40L) bf16 (tiled); Lp = partial row sums ====
// grid (Nn/64, 2 mhalf, Bb), block 512 = 8 waves; wave = 256 m x 64 n.
__global__ __launch_bounds__(512) void pass1(
    const unsigned short* __restrict__ Ft, const unsigned short* __restrict__ Gt,
    unsigned short* __restrict__ Et, float* __restrict__ Lp)
{
  __shared__ float red[8][64];
  const int n0 = blockIdx.x * 64;
  const int mh = blockIdx.y;
  const int b  = blockIdx.z;
  const int tid = threadIdx.x, wave = tid >> 6, lane = tid & 63;
  const int q = lane >> 4, col = lane & 15;
  const unsigned short* Fb = Ft + (size_t)b*Nn*K;
  const unsigned short* Gb = Gt + (size_t)b*Nn*K;
  unsigned short* Ebt = Et + (size_t)b*Nn*Nn;

  short8 af[4];
#pragma unroll
  for (int rb = 0; rb < 4; ++rb)
    af[rb] = *(const short8*)(Fb + (size_t)(n0 + rb*16 + col)*K + q*8);

  const int mw = mh*2048 + wave*256;     // 16 its x 16 m
  const f32x4 cinit = {-C40L, -C40L, -C40L, -C40L};
  float l[16];
#pragma unroll
  for (int i = 0; i < 16; ++i) l[i] = 0.f;

  unsigned short* sbase = Ebt + (size_t)(n0 >> 3)*128
                        + (q >> 1)*128 + col*8 + (q & 1)*4;

  short8 gA = *(const short8*)(Gb + (size_t)(mw + col)*K + q*8);
  for (int it = 0; it < 16; ++it) {
    short8 gB = *(const short8*)(Gb + (size_t)(mw + ((it+1)&15)*16 + col)*K + q*8);
    f32x4 ts[4];
    ts[0] = MF(af[0], gA, cinit);
    ts[1] = MF(af[1], gA, cinit);
    ts[2] = MF(af[2], gA, cinit);
    ts[3] = MF(af[3], gA, cinit);
    const int mt = (mw >> 4) + it;
    unsigned short* sb = sbase + (size_t)mt * (Nn*16);
#pragma unroll
    for (int rb = 0; rb < 4; ++rb) {
      float e0 = ex2(ts[rb][0]), e1 = ex2(ts[rb][1]);
      float e2 = ex2(ts[rb][2]), e3 = ex2(ts[rb][3]);
      l[rb*4+0] += e0; l[rb*4+1] += e1; l[rb*4+2] += e2; l[rb*4+3] += e3;
      uint2v w = { pack2(e0, e1), pack2(e2, e3) };
      __builtin_nontemporal_store(w, (uint2v*)(sb + rb*256));
    }
    gA = gB;
  }
#pragma unroll
  for (int d = 1; d < 16; d <<= 1) {
#pragma unroll
    for (int i = 0; i < 16; ++i) l[i] += __shfl_xor(l[i], d);
  }
  if (col == 0) {
#pragma unroll
    for (int rb = 0; rb < 4; ++rb) {
      float4 v = {l[rb*4+0], l[rb*4+1], l[rb*4+2], l[rb*4+3]};
      *(float4*)&red[wave][rb*16 + q*4] = v;
    }
  }
  __syncthreads();
  if (tid < 64) {
    float t = 0.f;
#pragma unroll
    for (int w = 0; w < 8; ++w) t += red[w][tid];
    Lp[((size_t)mh*Bb + b)*Nn + n0 + tid] = t;
  }
}

// ===== sumL: L = Lp[0] + Lp[1] =============================================
__global__ __launch_bounds__(256) void sumL(
    const float* __restrict__ Lp, float* __restrict__ L)
{
  int i = blockIdx.x * 256 + threadIdx.x;
  L[i] = Lp[i] + Lp[(size_t)Bb*Nn + i];
}

// ===== proj_hT: Htile = gamma*(Wh x + bh)/L[n] (A-operand tiled layout) ====
__global__ __launch_bounds__(256) void proj_hT(
    const unsigned short* __restrict__ xT, const unsigned short* __restrict__ Whb,
    const float* __restrict__ bh, const float* __restrict__ L,
    const float* __restrict__ gamma, unsigned short* __restrict__ Ht)
{
  const int b   = blockIdx.z;
  const int n0  = blockIdx.x * 64;
  const int c0  = blockIdx.y * 64;
  const int tid = threadIdx.x;
  const int wave = tid >> 6, lane = tid & 63;
  const int q = lane >> 4, col = lane & 15;
  const int nw = n0 + wave * 16;

  const unsigned short* Arow  = xT  + (size_t)(b*Nn + nw + col) * Cc + q*8;
  const unsigned short* Bbase = Whb + (size_t)(c0 + col) * Cc + q*8;

  const f32x4 zero = {0.f,0.f,0.f,0.f};
  f32x4 acc[4] = {zero, zero, zero, zero};

  short8 a0 = *(const short8*)(Arow);
  short8 b0[4], b1[4];
#pragma unroll
  for (int j = 0; j < 4; ++j) b0[j] = *(const short8*)(Bbase + (size_t)(j*16)*Cc);

  for (int ks = 0; ks < 256; ks += 64) {
    int k1 = (ks + 32) & 255;
    short8 a1 = *(const short8*)(Arow + k1);
#pragma unroll
    for (int j = 0; j < 4; ++j) b1[j] = *(const short8*)(Bbase + (size_t)(j*16)*Cc + k1);
#pragma unroll
    for (int j = 0; j < 4; ++j) acc[j] = MF(a0, b0[j], acc[j]);
    int k2 = (ks + 64) & 255;
    a0 = *(const short8*)(Arow + k2);
#pragma unroll
    for (int j = 0; j < 4; ++j) b0[j] = *(const short8*)(Bbase + (size_t)(j*16)*Cc + k2);
#pragma unroll
    for (int j = 0; j < 4; ++j) acc[j] = MF(a1, b1[j], acc[j]);
  }

  const float gm = gamma[0];
  float4 lv = *(const float4*)&L[(size_t)b*Nn + nw + q*4];
  float linv[4] = {gm/lv.x, gm/lv.y, gm/lv.z, gm/lv.w};
  unsigned short* Hbt = Ht + (size_t)b*Cc*Nn;
  unsigned short* wb = Hbt + (size_t)(nw >> 3)*128 + (q >> 1)*128 + col*8 + (q & 1)*4;
#pragma unroll
  for (int j = 0; j < 4; ++j) {
    float bb = bh[c0 + j*16 + col];
    float v0 = (acc[j][0] + bb) * linv[0];
    float v1 = (acc[j][1] + bb) * linv[1];
    float v2 = (acc[j][2] + bb) * linv[2];
    float v3 = (acc[j][3] + bb) * linv[3];
    uint2v w = { pack2(v0, v1), pack2(v2, v3) };
    *(uint2v*)(wb + (size_t)((c0 >> 4) + j) * (Nn*16)) = w;
  }
}

// ===== initX: out = x ======================================================
__global__ __launch_bounds__(256) void initX(
    const float* __restrict__ x, float* __restrict__ out)
{
  size_t i = ((size_t)blockIdx.x * 256 + threadIdx.x) * 4;
  float4 v = *(const float4*)&x[i];
  *(float4*)&out[i] = v;
}

// ===== out_gemm3: out += H'' @ E^T — split-K 4, BK=32, atomic epilogue =====
// grid 1024: ct = id>>9, r = id&511: mt = r>>4, b = (r>>2)&3, ks = r&3.
// block 256 = 4 waves, wave = 64c x 64m, 4x4 acc; 32 KB LDS double-buffer.
__global__ __launch_bounds__(256, 4) void out_gemm3(
    const unsigned short* __restrict__ Ht, const unsigned short* __restrict__ Et,
    float* __restrict__ out)
{
  __shared__ unsigned short As[2][4096];   // [buf][ct8(8)][no(4)][128el]
  __shared__ unsigned short Bs[2][4096];
  constexpr int TS = Nn * 16;              // tile-row stride (elements)

  const int id = blockIdx.x;
  const int ct = id >> 9;
  const int r  = id & 511;
  const int mt = r >> 4;
  const int b  = (r >> 2) & 3;
  const int ks = r & 3;
  const int c0 = ct * 128;
  const int m0 = mt * 128;
  const int nb16 = ks * 16384;             // n0*16 for n0 = ks*1024

  const int tid = threadIdx.x, wave = tid >> 6, lane = tid & 63;
  const int q = lane >> 4, col = lane & 15;
  const int wc = wave & 1, wm = wave >> 1;

  const unsigned short* Ag = Ht + (size_t)b*Cc*Nn + (size_t)(c0 >> 4)*TS + nb16;
  const unsigned short* Bg = Et + (size_t)b*Nn*Nn + (size_t)(m0 >> 4)*TS + nb16;

  // waves 0-1 stage A (4 x 1KB each), waves 2-3 stage B
  auto stage = [&](int buf, int t) {
    const int kb = t * 512;                // BK=32 -> 512 el per tile-row chunk
    if (wave < 2) {
      unsigned short* ld = &As[buf][0];
#pragma unroll
      for (int i = 0; i < 4; ++i) {
        int ct8 = wave*4 + i;
        stage16(Ag + (size_t)ct8*TS + kb + lane*8, ld + ct8*512);
      }
    } else {
      unsigned short* ld = &Bs[buf][0];
#pragma unroll
      for (int i = 0; i < 4; ++i) {
        int mt8 = (wave-2)*4 + i;
        stage16(Bg + (size_t)mt8*TS + kb + lane*8, ld + mt8*512);
      }
    }
  };

  const f32x4 zero = {0.f,0.f,0.f,0.f};
  f32x4 acc[4][4];
#pragma unroll
  for (int i = 0; i < 4; ++i)
#pragma unroll
    for (int j = 0; j < 4; ++j) acc[i][j] = zero;

  auto compute = [&](int buf) {
    short8 af[4], ef[4];
#pragma unroll
    for (int i = 0; i < 4; ++i) {
      af[i] = *(const short8*)&As[buf][(wc*4+i)*512 + q*128 + col*8];
      ef[i] = *(const short8*)&Bs[buf][(wm*4+i)*512 + q*128 + col*8];
    }
#pragma unroll
    for (int ci = 0; ci < 4; ++ci)
#pragma unroll
      for (int mi = 0; mi < 4; ++mi)
        acc[ci][mi] = MF(af[ci], ef[mi], acc[ci][mi]);
  };

  stage(0, 0);
  __syncthreads();
  for (int t = 0; t < 31; ++t) {
    stage((t + 1) & 1, t + 1);
    compute(t & 1);
    __syncthreads();
  }
  compute(1);

#pragma unroll
  for (int ci = 0; ci < 4; ++ci) {
#pragma unroll
    for (int mi = 0; mi < 4; ++mi) {
      const int m = m0 + wm*64 + mi*16 + col;
#pragma unroll
      for (int rr = 0; rr < 4; ++rr) {
        int c = c0 + wc*64 + ci*16 + q*4 + rr;
        atomicAdd(&out[((size_t)(b*Cc + c))*Nn + m], acc[ci][mi][rr]);
      }
    }
  }
}

// ======================== FALLBACK PATH (round-4 style) ====================
__global__ __launch_bounds__(256) void proj_h(
    const unsigned short* __restrict__ xT, const unsigned short* __restrict__ Whb,
    const float* __restrict__ bh, unsigned short* __restrict__ H)
{
  const int b   = blockIdx.z;
  const int n0  = blockIdx.x * 64;
  const int c0  = blockIdx.y * 64;
  const int tid = threadIdx.x;
  const int wave = tid >> 6, lane = tid & 63;
  const int q = lane >> 4, col = lane & 15;
  const int cw = c0 + wave * 16;

  const unsigned short* Arow = Whb + (size_t)(cw + col) * Cc + q*8;
  const unsigned short* Bbase = xT + (size_t)(b*Nn + n0 + col) * Cc + q*8;

  const f32x4 zero = {0.f,0.f,0.f,0.f};
  f32x4 acc[4] = {zero, zero, zero, zero};

  short8 a0 = *(const short8*)(Arow);
  short8 b0[4], b1[4];
#pragma unroll
  for (int j = 0; j < 4; ++j) b0[j] = *(const short8*)(Bbase + (size_t)(j*16)*Cc);

  for (int ks = 0; ks < 256; ks += 64) {
    int k1 = (ks + 32) & 255;
    short8 a1 = *(const short8*)(Arow + k1);
#pragma unroll
    for (int j = 0; j < 4; ++j) b1[j] = *(const short8*)(Bbase + (size_t)(j*16)*Cc + k1);
#pragma unroll
    for (int j = 0; j < 4; ++j) acc[j] = MF(a0, b0[j], acc[j]);
    int k2 = (ks + 64) & 255;
    a0 = *(const short8*)(Arow + k2);
#pragma unroll
    for (int j = 0; j < 4; ++j) b0[j] = *(const short8*)(Bbase + (size_t)(j*16)*Cc + k2);
#pragma unroll
    for (int j = 0; j < 4; ++j) acc[j] = MF(a1, b1[j], acc[j]);
  }

  float4 bb = *(const float4*)&bh[cw + q*4];
  float brs[4] = {bb.x, bb.y, bb.z, bb.w};
#pragma unroll
  for (int j = 0; j < 4; ++j) {
#pragma unroll
    for (int r = 0; r < 4; ++r) {
      int c = cw + q*4 + r;
      int n = n0 + j*16 + col;
      H[(size_t)(b*Cc + c)*Nn + n] = f2bf(acc[j][r] + brs[r]);
    }
  }
}

__global__ __launch_bounds__(256) void stats_k(
    const unsigned short* __restrict__ Ft, const unsigned short* __restrict__ Gt,
    float* __restrict__ Lp)
{
  __shared__ float red[4][32];
  const int b = blockIdx.y >> 1, ms = blockIdx.y & 1;
  const int n0 = blockIdx.x * 32;
  const int tid = threadIdx.x, wave = tid >> 6, lane = tid & 63;
  const int q = lane >> 4, col = lane & 15;
  const unsigned short* Fb = Ft + (size_t)b*Nn*K;
  const unsigned short* Gb = Gt + (size_t)b*Nn*K;

  short8 af0 = *(const short8*)(Fb + (size_t)(n0      + col)*K + q*8);
  short8 af1 = *(const short8*)(Fb + (size_t)(n0 + 16 + col)*K + q*8);
  const int mq = ms*2048 + wave*512;
  const f32x4 zero = {0.f,0.f,0.f,0.f};
  float l[8] = {0.f,0.f,0.f,0.f,0.f,0.f,0.f,0.f};

  short8 gfA = *(const short8*)(Gb + (size_t)(mq + col)*K + q*8);
  for (int it = 0; it < 32; ++it) {
    short8 gfB = *(const short8*)(Gb + (size_t)(mq + ((it+1)&31)*16 + col)*K + q*8);
    f32x4 s0 = MF(af0, gfA, zero);
    f32x4 s1 = MF(af1, gfA, zero);
#pragma unroll
    for (int r = 0; r < 4; ++r) {
      l[r]   += ex2(s0[r] - C40L);
      l[4+r] += ex2(s1[r] - C40L);
    }
    gfA = gfB;
  }
#pragma unroll
  for (int d = 1; d < 16; d <<= 1) {
#pragma unroll
    for (int r = 0; r < 8; ++r) l[r] += __shfl_xor(l[r], d);
  }
  if (col == 0) {
    float4 v0 = {l[0], l[1], l[2], l[3]};
    float4 v1 = {l[4], l[5], l[6], l[7]};
    *(float4*)&red[wave][q*4]      = v0;
    *(float4*)&red[wave][16 + q*4] = v1;
  }
  __syncthreads();
  if (tid < 32) {
    float t = red[0][tid] + red[1][tid] + red[2][tid] + red[3][tid];
    Lp[((size_t)ms*Bb + b)*Nn + n0 + tid] = t;
  }
}

__global__ __launch_bounds__(256) void zcomb(
    const float* __restrict__ Lp, float* __restrict__ Z2)
{
  int i = blockIdx.x * 256 + threadIdx.x;
  Z2[i] = C40L + __log2f(Lp[i] + Lp[(size_t)Bb*Nn + i]);
}

struct Gen { short8 af0, af1; short8 hf[4]; };

__global__ __launch_bounds__(256, 4) void out_k(
    const unsigned short* __restrict__ Ft, const unsigned short* __restrict__ Gt,
    const unsigned short* __restrict__ H, const float* __restrict__ Z2,
    const float* __restrict__ x, const float* __restrict__ gamma,
    float* __restrict__ dst)
{
  __shared__ unsigned short Ps[4][32*40];
  const int b   = blockIdx.y;
  const int m0  = blockIdx.x * 64;
  const int c0b = blockIdx.z * 128;
  const int tid = threadIdx.x, wave = tid >> 6, lane = tid & 63;
  const int q = lane >> 4, col = lane & 15;
  const int mw  = m0 + (wave & 1) * 32;
  const int c0w = c0b + (wave >> 1) * 64;

  const unsigned short* Fb = Ft + (size_t)b*Nn*K;
  const unsigned short* Hb = H  + (size_t)b*Cc*Nn;
  const float*          Zb = Z2 + (size_t)b*Nn;

  short8 gf0 = *(const short8*)(Gt + (size_t)(b*Nn + mw      + col)*K + q*8);
  short8 gf1 = *(const short8*)(Gt + (size_t)(b*Nn + mw + 16 + col)*K + q*8);

  unsigned short* Pw = &Ps[wave][0];
  const f32x4 zero = {0.f,0.f,0.f,0.f};
  f32x4 acc[2][4];
#pragma unroll
  for (int j = 0; j < 2; ++j)
#pragma unroll
    for (int i = 0; i < 4; ++i) acc[j][i] = zero;

  Gen A, B;
  auto loadGen = [&](Gen& G, int nt) {
    G.af0 = *(const short8*)(Fb + (size_t)(nt      + col)*K + q*8);
    G.af1 = *(const short8*)(Fb + (size_t)(nt + 16 + col)*K + q*8);
#pragma unroll
    for (int i = 0; i < 4; ++i)
      G.hf[i] = *(const short8*)(Hb + (size_t)(c0w + i*16 + col)*Nn + nt + q*8);
  };
  auto step = [&](int nt, Gen& CUR, Gen& NXT) {
    loadGen(NXT, (nt + 32) & (Nn - 1));
    float4 z0 = *(const float4*)(Zb + nt + q*4);
    float4 z1 = *(const float4*)(Zb + nt + 16 + q*4);
    f32x4 s00 = MF(CUR.af0, gf0, zero);
    f32x4 s01 = MF(CUR.af0, gf1, zero);
    f32x4 s10 = MF(CUR.af1, gf0, zero);
    f32x4 s11 = MF(CUR.af1, gf1, zero);
    uint2 w00 = { pack2(ex2(s00[0]-z0.x), ex2(s00[1]-z0.y)),
                  pack2(ex2(s00[2]-z0.z), ex2(s00[3]-z0.w)) };
    uint2 w01 = { pack2(ex2(s01[0]-z0.x), ex2(s01[1]-z0.y)),
                  pack2(ex2(s01[2]-z0.z), ex2(s01[3]-z0.w)) };
    uint2 w10 = { pack2(ex2(s10[0]-z1.x), ex2(s10[1]-z1.y)),
                  pack2(ex2(s10[2]-z1.z), ex2(s10[3]-z1.w)) };
    uint2 w11 = { pack2(ex2(s11[0]-z1.x), ex2(s11[1]-z1.y)),
                  pack2(ex2(s11[2]-z1.z), ex2(s11[3]-z1.w)) };
    *(uint2*)&Pw[(     col)*40      + q*4] = w00;
    *(uint2*)&Pw[(16 + col)*40      + q*4] = w01;
    *(uint2*)&Pw[(     col)*40 + 16 + q*4] = w10;
    *(uint2*)&Pw[(16 + col)*40 + 16 + q*4] = w11;
    short8 pf0 = *(const short8*)&Pw[(     col)*40 + q*8];
    short8 pf1 = *(const short8*)&Pw[(16 + col)*40 + q*8];
#pragma unroll
    for (int i = 0; i < 4; ++i) {
      acc[0][i] = MF(CUR.hf[i], pf0, acc[0][i]);
      acc[1][i] = MF(CUR.hf[i], pf1, acc[1][i]);
    }
  };

  loadGen(A, 0);
  for (int t = 0; t < 128; t += 2) {
    step(t*32,      A, B);
    step(t*32 + 32, B, A);
  }

  const float gm = gamma[0];
#pragma unroll
  for (int mj = 0; mj < 2; ++mj) {
    const int m = mw + mj*16 + col;
#pragma unroll
    for (int i = 0; i < 4; ++i) {
#pragma unroll
      for (int r = 0; r < 4; ++r) {
        int c = c0w + i*16 + q*4 + r;
        size_t idx = ((size_t)(b*Cc + c))*Nn + m;
        dst[idx] = fmaf(gm, acc[mj][i][r], x[idx]);
      }
    }
  }
}

// ===========================================================================
extern "C" void kernel_launch(void* const* d_in, const int* in_sizes, int n_in,
                              void* d_out, int out_size, void* d_ws, size_t ws_size,
                              hipStream_t stream) {
  (void)in_sizes; (void)n_in; (void)out_size;
  const float* x     = (const float*)d_in[0];
  const float* Wf    = (const float*)d_in[1];
  const float* bf    = (const float*)d_in[2];
  const float* Wg    = (const float*)d_in[3];
  const float* bg    = (const float*)d_in[4];
  const float* Wh    = (const float*)d_in[5];
  const float* bh    = (const float*)d_in[6];
  const float* gamma = (const float*)d_in[7];
  float* out = (float*)d_out;

  unsigned short* Ft   = (unsigned short*)d_ws;                // 524288 el
  unsigned short* Gt   = Ft   + (size_t)Bb*Nn*K;               // 524288 el
  unsigned short* xT   = Gt   + (size_t)Bb*Nn*K;               // 4194304 el
  unsigned short* H    = xT   + (size_t)Bb*Nn*Cc;              // 4194304 el
  unsigned short* Whb  = H    + (size_t)Bb*Cc*Nn;              // 65536 el
  unsigned short* Wfgb = Whb  + (size_t)Cc*Cc;                 // 16384 el
  float*          L    = (float*)(Wfgb + 64*Cc);               // 16384 f
  float*          Z2   = L  + (size_t)Bb*Nn;                   // 16384 f
  float*          Lp   = Z2 + (size_t)Bb*Nn;                   // 32768 f
  unsigned short* Et   = (unsigned short*)(Lp + 2*(size_t)Bb*Nn);  // 128 MB

  const size_t baseEnd = 19038208ull + 65536ull*4;             // 19300352
  const size_t needE   = baseEnd + (size_t)Bb*Nn*Nn*2;         // ~153.5 MB

  castW   <<<dim3(Cc*Cc/1024), 256, 0, stream>>>(Wh, Whb);
  castFG  <<<dim3(64*Cc/1024), 256, 0, stream>>>(Wf, Wg, Wfgb);
  trans_k <<<dim3(Nn/64, Cc/64, Bb), 256, 0, stream>>>(x, xT);
  proj_fgM<<<dim3(Nn/64, Bb), 256, 0, stream>>>(xT, Wfgb, bf, bg, Ft, Gt);

  if (ws_size >= needE) {
    pass1    <<<dim3(Nn/64, 2, Bb), 512, 0, stream>>>(Ft, Gt, Et, Lp);
    sumL     <<<dim3(Bb*Nn/256), 256, 0, stream>>>(Lp, L);
    proj_hT  <<<dim3(Nn/64, Cc/64, Bb), 256, 0, stream>>>(xT, Whb, bh, L, gamma, H);
    initX    <<<dim3((size_t)Bb*Cc*Nn/1024), 256, 0, stream>>>(x, out);
    out_gemm3<<<dim3(1024), 256, 0, stream>>>(H, Et, out);
  } else {
    proj_h  <<<dim3(Nn/64, Cc/64, Bb), 256, 0, stream>>>(xT, Whb, bh, H);
    stats_k <<<dim3(Nn/32, 2*Bb), 256, 0, stream>>>(Ft, Gt, Lp);
    zcomb   <<<dim3(Bb*Nn/256), 256, 0, stream>>>(Lp, Z2);
    out_k   <<<dim3(Nn/64, Bb, 2), 256, 0, stream>>>(Ft, Gt, H, Z2, x, gamma, out);
  }
}

// Round 11
// 210.191 us; speedup vs baseline: 1.1183x; 1.1183x over previous
//
#include <hip/hip_runtime.h>
#include <hip/hip_bf16.h>
#include <math.h>

// Problem constants (fixed by the reference)
constexpr int Bb = 4;      // batch
constexpr int Cc = 256;    // channels
constexpr int Nn = 4096;   // sequence positions
constexpr int K  = 32;     // qk channels

constexpr float LOG2E = 1.4426950408889634f;
constexpr float C40L  = 40.0f * LOG2E;   // softmax shift, log2 domain

typedef __attribute__((ext_vector_type(8))) short short8;   // 8 x bf16
typedef __attribute__((ext_vector_type(4))) float f32x4;    // MFMA C/D
typedef __attribute__((ext_vector_type(2))) unsigned int uint2v;

static __device__ __forceinline__ unsigned int pack2(float a, float b) {
  union { __hip_bfloat162 h2; unsigned int u; } cv;
  cv.h2 = __float22bfloat162_rn(float2{a, b});
  return cv.u;
}
static __device__ __forceinline__ unsigned short f2bf(float f) {
  union { __hip_bfloat16 h; unsigned short u; } cv;
  cv.h = __float2bfloat16(f);
  return cv.u;
}
static __device__ __forceinline__ f32x4 MF(short8 a, short8 b, f32x4 c) {
  return __builtin_amdgcn_mfma_f32_16x16x32_bf16(a, b, c, 0, 0, 0);
}
static __device__ __forceinline__ float ex2(float v) {
  return __builtin_amdgcn_exp2f(v);
}
// async global->LDS, 16B per lane; LDS dest = wave-uniform base + lane*16
static __device__ __forceinline__ void stage16(const unsigned short* g,
                                               unsigned short* l) {
  __builtin_amdgcn_global_load_lds(
      (const __attribute__((address_space(1))) unsigned int*)g,
      (__attribute__((address_space(3))) unsigned int*)l, 16, 0, 0);
}

// ---------------------------------------------------------------------------
// TILED fragment layouts (primary path):
//   Etile[b][mt=m/16][no=n/8][ml=m&15][ne=n&7]  bf16   (B-operand order)
//   Htile[b][ct=c/16][no=n/8][cl=c&15][ne=n&7]  bf16   (A-operand order,
//         H'' = gamma*h/L folded)
// Element offset of n-position n0 within a tile-row: (n0/8)*128 = n0*16.
// ---------------------------------------------------------------------------

// ===== castW: Wh fp32 -> bf16 ==============================================
__global__ __launch_bounds__(256) void castW(
    const float* __restrict__ Wh, unsigned short* __restrict__ Whb)
{
  int i = (blockIdx.x * 256 + threadIdx.x) * 4;
  float4 v = *(const float4*)&Wh[i];
  uint2 o = { pack2(v.x, v.y), pack2(v.z, v.w) };
  *(uint2*)&Whb[i] = o;
}

// ===== castFG: Wf,Wg fp32 -> Wfgb bf16 =====================================
__global__ __launch_bounds__(256) void castFG(
    const float* __restrict__ Wf, const float* __restrict__ Wg,
    unsigned short* __restrict__ Wfgb)
{
  int g = (blockIdx.x * 256 + threadIdx.x) * 4;
  int row = g >> 8, c = g & 255;
  const float* src = (row < 32) ? &Wf[row*Cc + c] : &Wg[(row-32)*Cc + c];
  float4 v = *(const float4*)src;
  uint2 o = { pack2(v.x, v.y), pack2(v.z, v.w) };
  *(uint2*)&Wfgb[g] = o;
}

// ===== trans_k: xT[b][n][c] = bf16(x[b][c][n]); also out = x ===============
__global__ __launch_bounds__(256) void trans_k(
    const float* __restrict__ x, unsigned short* __restrict__ xT,
    float* __restrict__ outInit)
{
  __shared__ unsigned short Ls[64][65];
  const int b  = blockIdx.z;
  const int n0 = blockIdx.x * 64, c0 = blockIdx.y * 64;
  const int tid = threadIdx.x;
  {
    const int cr = tid >> 4, n4 = (tid & 15) * 4;
#pragma unroll
    for (int rr = 0; rr < 4; ++rr) {
      int c = rr * 16 + cr;
      size_t idx = (size_t)(b*Cc + c0 + c)*Nn + n0 + n4;
      float4 v = *(const float4*)&x[idx];
      *(float4*)&outInit[idx] = v;          // pre-init out with residual x
      Ls[c][n4+0] = f2bf(v.x); Ls[c][n4+1] = f2bf(v.y);
      Ls[c][n4+2] = f2bf(v.z); Ls[c][n4+3] = f2bf(v.w);
    }
  }
  __syncthreads();
  {
    const int nw = tid >> 4, cw = (tid & 15) * 4;
#pragma unroll
    for (int rr = 0; rr < 4; ++rr) {
      int n = nw + rr * 16;
      unsigned int lo = (unsigned int)Ls[cw+0][n] | ((unsigned int)Ls[cw+1][n] << 16);
      unsigned int hi = (unsigned int)Ls[cw+2][n] | ((unsigned int)Ls[cw+3][n] << 16);
      uint2 o = { lo, hi };
      *(uint2*)&xT[(size_t)(b*Nn + n0 + n)*Cc + c0 + cw] = o;
    }
  }
}

// ===== proj_fgM: F' = LOG2E*(Wf x + bf), G = Wg x + bg via MFMA ============
__global__ __launch_bounds__(256) void proj_fgM(
    const unsigned short* __restrict__ xT, const unsigned short* __restrict__ Wfgb,
    const float* __restrict__ bf, const float* __restrict__ bg,
    unsigned short* __restrict__ Ft, unsigned short* __restrict__ Gt)
{
  const int b = blockIdx.y;
  const int tid = threadIdx.x, wave = tid >> 6, lane = tid & 63;
  const int q = lane >> 4, col = lane & 15;
  const int n = blockIdx.x * 64 + wave * 16 + col;

  const unsigned short* Bp = xT + (size_t)(b*Nn + n)*Cc + q*8;
  const f32x4 zero = {0.f,0.f,0.f,0.f};
  f32x4 af0 = zero, af1 = zero, ag0 = zero, ag1 = zero;
#pragma unroll
  for (int kc = 0; kc < 8; ++kc) {
    short8 bn = *(const short8*)(Bp + kc*32);
    short8 a0 = *(const short8*)(Wfgb + (size_t)( 0 + col)*Cc + kc*32 + q*8);
    short8 a1 = *(const short8*)(Wfgb + (size_t)(16 + col)*Cc + kc*32 + q*8);
    short8 a2 = *(const short8*)(Wfgb + (size_t)(32 + col)*Cc + kc*32 + q*8);
    short8 a3 = *(const short8*)(Wfgb + (size_t)(48 + col)*Cc + kc*32 + q*8);
    af0 = MF(a0, bn, af0); af1 = MF(a1, bn, af1);
    ag0 = MF(a2, bn, ag0); ag1 = MF(a3, bn, ag1);
  }
  float4 bf0 = *(const float4*)&bf[q*4],      bf1 = *(const float4*)&bf[16 + q*4];
  float4 bg0 = *(const float4*)&bg[q*4],      bg1 = *(const float4*)&bg[16 + q*4];
  uint2 F0 = { pack2((af0[0]+bf0.x)*LOG2E, (af0[1]+bf0.y)*LOG2E),
               pack2((af0[2]+bf0.z)*LOG2E, (af0[3]+bf0.w)*LOG2E) };
  uint2 F1 = { pack2((af1[0]+bf1.x)*LOG2E, (af1[1]+bf1.y)*LOG2E),
               pack2((af1[2]+bf1.z)*LOG2E, (af1[3]+bf1.w)*LOG2E) };
  uint2 G0 = { pack2(ag0[0]+bg0.x, ag0[1]+bg0.y), pack2(ag0[2]+bg0.z, ag0[3]+bg0.w) };
  uint2 G1 = { pack2(ag1[0]+bg1.x, ag1[1]+bg1.y), pack2(ag1[2]+bg1.z, ag1[3]+bg1.w) };
  unsigned short* fo = Ft + (size_t)(b*Nn + n)*K;
  unsigned short* go = Gt + (size_t)(b*Nn + n)*K;
  *(uint2*)(fo + q*4) = F0;  *(uint2*)(fo + 16 + q*4) = F1;
  *(uint2*)(go + q*4) = G0;  *(uint2*)(go + 16 + q*4) = G1;
}

// ===== pass1: Etile = exp2(S'-C40L) bf16 (tiled); Lp = partial row sums ====
// grid (Nn/64, 2 mhalf, Bb), block 512 = 8 waves; wave = 256 m x 64 n.
__global__ __launch_bounds__(512) void pass1(
    const unsigned short* __restrict__ Ft, const unsigned short* __restrict__ Gt,
    unsigned short* __restrict__ Et, float* __restrict__ Lp)
{
  __shared__ float red[8][64];
  const int n0 = blockIdx.x * 64;
  const int mh = blockIdx.y;
  const int b  = blockIdx.z;
  const int tid = threadIdx.x, wave = tid >> 6, lane = tid & 63;
  const int q = lane >> 4, col = lane & 15;
  const unsigned short* Fb = Ft + (size_t)b*Nn*K;
  const unsigned short* Gb = Gt + (size_t)b*Nn*K;
  unsigned short* Ebt = Et + (size_t)b*Nn*Nn;

  short8 af[4];
#pragma unroll
  for (int rb = 0; rb < 4; ++rb)
    af[rb] = *(const short8*)(Fb + (size_t)(n0 + rb*16 + col)*K + q*8);

  const int mw = mh*2048 + wave*256;     // 16 its x 16 m
  const f32x4 cinit = {-C40L, -C40L, -C40L, -C40L};
  float l[16];
#pragma unroll
  for (int i = 0; i < 16; ++i) l[i] = 0.f;

  unsigned short* sbase = Ebt + (size_t)(n0 >> 3)*128
                        + (q >> 1)*128 + col*8 + (q & 1)*4;

  short8 gA = *(const short8*)(Gb + (size_t)(mw + col)*K + q*8);
  for (int it = 0; it < 16; ++it) {
    short8 gB = *(const short8*)(Gb + (size_t)(mw + ((it+1)&15)*16 + col)*K + q*8);
    f32x4 ts[4];
    ts[0] = MF(af[0], gA, cinit);
    ts[1] = MF(af[1], gA, cinit);
    ts[2] = MF(af[2], gA, cinit);
    ts[3] = MF(af[3], gA, cinit);
    const int mt = (mw >> 4) + it;
    unsigned short* sb = sbase + (size_t)mt * (Nn*16);
#pragma unroll
    for (int rb = 0; rb < 4; ++rb) {
      float e0 = ex2(ts[rb][0]), e1 = ex2(ts[rb][1]);
      float e2 = ex2(ts[rb][2]), e3 = ex2(ts[rb][3]);
      l[rb*4+0] += e0; l[rb*4+1] += e1; l[rb*4+2] += e2; l[rb*4+3] += e3;
      uint2v w = { pack2(e0, e1), pack2(e2, e3) };
      __builtin_nontemporal_store(w, (uint2v*)(sb + rb*256));
    }
    gA = gB;
  }
#pragma unroll
  for (int d = 1; d < 16; d <<= 1) {
#pragma unroll
    for (int i = 0; i < 16; ++i) l[i] += __shfl_xor(l[i], d);
  }
  if (col == 0) {
#pragma unroll
    for (int rb = 0; rb < 4; ++rb) {
      float4 v = {l[rb*4+0], l[rb*4+1], l[rb*4+2], l[rb*4+3]};
      *(float4*)&red[wave][rb*16 + q*4] = v;
    }
  }
  __syncthreads();
  if (tid < 64) {
    float t = 0.f;
#pragma unroll
    for (int w = 0; w < 8; ++w) t += red[w][tid];
    Lp[((size_t)mh*Bb + b)*Nn + n0 + tid] = t;
  }
}

// ===== sumL: L = Lp[0] + Lp[1] =============================================
__global__ __launch_bounds__(256) void sumL(
    const float* __restrict__ Lp, float* __restrict__ L)
{
  int i = blockIdx.x * 256 + threadIdx.x;
  L[i] = Lp[i] + Lp[(size_t)Bb*Nn + i];
}

// ===== proj_hT: Htile = gamma*(Wh x + bh)/L[n] (A-operand tiled layout) ====
__global__ __launch_bounds__(256) void proj_hT(
    const unsigned short* __restrict__ xT, const unsigned short* __restrict__ Whb,
    const float* __restrict__ bh, const float* __restrict__ L,
    const float* __restrict__ gamma, unsigned short* __restrict__ Ht)
{
  const int b   = blockIdx.z;
  const int n0  = blockIdx.x * 64;
  const int c0  = blockIdx.y * 64;
  const int tid = threadIdx.x;
  const int wave = tid >> 6, lane = tid & 63;
  const int q = lane >> 4, col = lane & 15;
  const int nw = n0 + wave * 16;

  const unsigned short* Arow  = xT  + (size_t)(b*Nn + nw + col) * Cc + q*8;
  const unsigned short* Bbase = Whb + (size_t)(c0 + col) * Cc + q*8;

  const f32x4 zero = {0.f,0.f,0.f,0.f};
  f32x4 acc[4] = {zero, zero, zero, zero};

  short8 a0 = *(const short8*)(Arow);
  short8 b0[4], b1[4];
#pragma unroll
  for (int j = 0; j < 4; ++j) b0[j] = *(const short8*)(Bbase + (size_t)(j*16)*Cc);

  for (int ks = 0; ks < 256; ks += 64) {
    int k1 = (ks + 32) & 255;
    short8 a1 = *(const short8*)(Arow + k1);
#pragma unroll
    for (int j = 0; j < 4; ++j) b1[j] = *(const short8*)(Bbase + (size_t)(j*16)*Cc + k1);
#pragma unroll
    for (int j = 0; j < 4; ++j) acc[j] = MF(a0, b0[j], acc[j]);
    int k2 = (ks + 64) & 255;
    a0 = *(const short8*)(Arow + k2);
#pragma unroll
    for (int j = 0; j < 4; ++j) b0[j] = *(const short8*)(Bbase + (size_t)(j*16)*Cc + k2);
#pragma unroll
    for (int j = 0; j < 4; ++j) acc[j] = MF(a1, b1[j], acc[j]);
  }

  const float gm = gamma[0];
  float4 lv = *(const float4*)&L[(size_t)b*Nn + nw + q*4];
  float linv[4] = {gm/lv.x, gm/lv.y, gm/lv.z, gm/lv.w};
  unsigned short* Hbt = Ht + (size_t)b*Cc*Nn;
  unsigned short* wb = Hbt + (size_t)(nw >> 3)*128 + (q >> 1)*128 + col*8 + (q & 1)*4;
#pragma unroll
  for (int j = 0; j < 4; ++j) {
    float bb = bh[c0 + j*16 + col];
    float v0 = (acc[j][0] + bb) * linv[0];
    float v1 = (acc[j][1] + bb) * linv[1];
    float v2 = (acc[j][2] + bb) * linv[2];
    float v3 = (acc[j][3] + bb) * linv[3];
    uint2v w = { pack2(v0, v1), pack2(v2, v3) };
    *(uint2v*)(wb + (size_t)((c0 >> 4) + j) * (Nn*16)) = w;
  }
}

// ===== out_gemm4: out += H'' @ E^T — split-K 2, BK=64, atomic epilogue =====
// grid 512: xcd = id&7 -> (b = xcd>>1, ks = xcd&1); s = id>>3 -> ct(2) x mt(32).
// block 256 = 4 waves, wave = 64c x 64m, 4x4 acc; 64 KB LDS double-buffer.
// K-span 2048 per block -> 32 steps of BK=64.
__global__ __launch_bounds__(256, 2) void out_gemm4(
    const unsigned short* __restrict__ Ht, const unsigned short* __restrict__ Et,
    float* __restrict__ out)
{
  __shared__ unsigned short As[2][8192];   // [buf][ct8(8)][1024el = 64n]
  __shared__ unsigned short Bs[2][8192];
  constexpr int TS = Nn * 16;              // tile-row stride (elements)

  const int id  = blockIdx.x;
  const int xcd = id & 7;
  const int b   = xcd >> 1;                // batch per XCD pair
  const int ks  = xcd & 1;                 // K-half per XCD within the pair
  const int s   = id >> 3;                 // 0..63
  const int ct  = s >> 5;                  // 0..1
  const int mt  = s & 31;                  // 0..31
  const int c0 = ct * 128;
  const int m0 = mt * 128;
  const int nb16 = ks * 32768;             // n0*16 for n0 = ks*2048

  const int tid = threadIdx.x, wave = tid >> 6, lane = tid & 63;
  const int q = lane >> 4, col = lane & 15;
  const int wc = wave & 1, wm = wave >> 1;

  const unsigned short* Ag = Ht + (size_t)b*Cc*Nn + (size_t)(c0 >> 4)*TS + nb16;
  const unsigned short* Bg = Et + (size_t)b*Nn*Nn + (size_t)(m0 >> 4)*TS + nb16;

  // waves 0-1 stage A (8 x 1KB each), waves 2-3 stage B
  auto stage = [&](int buf, int t) {
    const int kb = t * 1024;               // BK=64 -> 1024 el per tile-row chunk
    if (wave < 2) {
      unsigned short* ld = &As[buf][0];
#pragma unroll
      for (int i = 0; i < 8; ++i) {
        int j = wave*8 + i, ct8 = j >> 1, h2 = j & 1;
        stage16(Ag + (size_t)ct8*TS + kb + h2*512 + lane*8,
                ld + ct8*1024 + h2*512);
      }
    } else {
      unsigned short* ld = &Bs[buf][0];
#pragma unroll
      for (int i = 0; i < 8; ++i) {
        int j = (wave-2)*8 + i, mt8 = j >> 1, h2 = j & 1;
        stage16(Bg + (size_t)mt8*TS + kb + h2*512 + lane*8,
                ld + mt8*1024 + h2*512);
      }
    }
  };

  const f32x4 zero = {0.f,0.f,0.f,0.f};
  f32x4 acc[4][4];
#pragma unroll
  for (int i = 0; i < 4; ++i)
#pragma unroll
    for (int j = 0; j < 4; ++j) acc[i][j] = zero;

  auto compute = [&](int buf) {
#pragma unroll
    for (int kc = 0; kc < 2; ++kc) {
      short8 af[4], ef[4];
#pragma unroll
      for (int i = 0; i < 4; ++i) {
        af[i] = *(const short8*)&As[buf][(wc*4+i)*1024 + (kc*4+q)*128 + col*8];
        ef[i] = *(const short8*)&Bs[buf][(wm*4+i)*1024 + (kc*4+q)*128 + col*8];
      }
#pragma unroll
      for (int ci = 0; ci < 4; ++ci)
#pragma unroll
        for (int mi = 0; mi < 4; ++mi)
          acc[ci][mi] = MF(af[ci], ef[mi], acc[ci][mi]);
    }
  };

  stage(0, 0);
  __syncthreads();
  for (int t = 0; t < 31; ++t) {
    stage((t + 1) & 1, t + 1);
    compute(t & 1);
    __syncthreads();
  }
  compute(1);

#pragma unroll
  for (int ci = 0; ci < 4; ++ci) {
#pragma unroll
    for (int mi = 0; mi < 4; ++mi) {
      const int m = m0 + wm*64 + mi*16 + col;
#pragma unroll
      for (int rr = 0; rr < 4; ++rr) {
        int c = c0 + wc*64 + ci*16 + q*4 + rr;
        atomicAdd(&out[((size_t)(b*Cc + c))*Nn + m], acc[ci][mi][rr]);
      }
    }
  }
}

// ======================== FALLBACK PATH (round-4 style) ====================
__global__ __launch_bounds__(256) void proj_h(
    const unsigned short* __restrict__ xT, const unsigned short* __restrict__ Whb,
    const float* __restrict__ bh, unsigned short* __restrict__ H)
{
  const int b   = blockIdx.z;
  const int n0  = blockIdx.x * 64;
  const int c0  = blockIdx.y * 64;
  const int tid = threadIdx.x;
  const int wave = tid >> 6, lane = tid & 63;
  const int q = lane >> 4, col = lane & 15;
  const int cw = c0 + wave * 16;

  const unsigned short* Arow = Whb + (size_t)(cw + col) * Cc + q*8;
  const unsigned short* Bbase = xT + (size_t)(b*Nn + n0 + col) * Cc + q*8;

  const f32x4 zero = {0.f,0.f,0.f,0.f};
  f32x4 acc[4] = {zero, zero, zero, zero};

  short8 a0 = *(const short8*)(Arow);
  short8 b0[4], b1[4];
#pragma unroll
  for (int j = 0; j < 4; ++j) b0[j] = *(const short8*)(Bbase + (size_t)(j*16)*Cc);

  for (int ks = 0; ks < 256; ks += 64) {
    int k1 = (ks + 32) & 255;
    short8 a1 = *(const short8*)(Arow + k1);
#pragma unroll
    for (int j = 0; j < 4; ++j) b1[j] = *(const short8*)(Bbase + (size_t)(j*16)*Cc + k1);
#pragma unroll
    for (int j = 0; j < 4; ++j) acc[j] = MF(a0, b0[j], acc[j]);
    int k2 = (ks + 64) & 255;
    a0 = *(const short8*)(Arow + k2);
#pragma unroll
    for (int j = 0; j < 4; ++j) b0[j] = *(const short8*)(Bbase + (size_t)(j*16)*Cc + k2);
#pragma unroll
    for (int j = 0; j < 4; ++j) acc[j] = MF(a1, b1[j], acc[j]);
  }

  float4 bb = *(const float4*)&bh[cw + q*4];
  float brs[4] = {bb.x, bb.y, bb.z, bb.w};
#pragma unroll
  for (int j = 0; j < 4; ++j) {
#pragma unroll
    for (int r = 0; r < 4; ++r) {
      int c = cw + q*4 + r;
      int n = n0 + j*16 + col;
      H[(size_t)(b*Cc + c)*Nn + n] = f2bf(acc[j][r] + brs[r]);
    }
  }
}

__global__ __launch_bounds__(256) void stats_k(
    const unsigned short* __restrict__ Ft, const unsigned short* __restrict__ Gt,
    float* __restrict__ Lp)
{
  __shared__ float red[4][32];
  const int b = blockIdx.y >> 1, ms = blockIdx.y & 1;
  const int n0 = blockIdx.x * 32;
  const int tid = threadIdx.x, wave = tid >> 6, lane = tid & 63;
  const int q = lane >> 4, col = lane & 15;
  const unsigned short* Fb = Ft + (size_t)b*Nn*K;
  const unsigned short* Gb = Gt + (size_t)b*Nn*K;

  short8 af0 = *(const short8*)(Fb + (size_t)(n0      + col)*K + q*8);
  short8 af1 = *(const short8*)(Fb + (size_t)(n0 + 16 + col)*K + q*8);
  const int mq = ms*2048 + wave*512;
  const f32x4 zero = {0.f,0.f,0.f,0.f};
  float l[8] = {0.f,0.f,0.f,0.f,0.f,0.f,0.f,0.f};

  short8 gfA = *(const short8*)(Gb + (size_t)(mq + col)*K + q*8);
  for (int it = 0; it < 32; ++it) {
    short8 gfB = *(const short8*)(Gb + (size_t)(mq + ((it+1)&31)*16 + col)*K + q*8);
    f32x4 s0 = MF(af0, gfA, zero);
    f32x4 s1 = MF(af1, gfA, zero);
#pragma unroll
    for (int r = 0; r < 4; ++r) {
      l[r]   += ex2(s0[r] - C40L);
      l[4+r] += ex2(s1[r] - C40L);
    }
    gfA = gfB;
  }
#pragma unroll
  for (int d = 1; d < 16; d <<= 1) {
#pragma unroll
    for (int r = 0; r < 8; ++r) l[r] += __shfl_xor(l[r], d);
  }
  if (col == 0) {
    float4 v0 = {l[0], l[1], l[2], l[3]};
    float4 v1 = {l[4], l[5], l[6], l[7]};
    *(float4*)&red[wave][q*4]      = v0;
    *(float4*)&red[wave][16 + q*4] = v1;
  }
  __syncthreads();
  if (tid < 32) {
    float t = red[0][tid] + red[1][tid] + red[2][tid] + red[3][tid];
    Lp[((size_t)ms*Bb + b)*Nn + n0 + tid] = t;
  }
}

__global__ __launch_bounds__(256) void zcomb(
    const float* __restrict__ Lp, float* __restrict__ Z2)
{
  int i = blockIdx.x * 256 + threadIdx.x;
  Z2[i] = C40L + __log2f(Lp[i] + Lp[(size_t)Bb*Nn + i]);
}

struct Gen { short8 af0, af1; short8 hf[4]; };

__global__ __launch_bounds__(256, 4) void out_k(
    const unsigned short* __restrict__ Ft, const unsigned short* __restrict__ Gt,
    const unsigned short* __restrict__ H, const float* __restrict__ Z2,
    const float* __restrict__ x, const float* __restrict__ gamma,
    float* __restrict__ dst)
{
  __shared__ unsigned short Ps[4][32*40];
  const int b   = blockIdx.y;
  const int m0  = blockIdx.x * 64;
  const int c0b = blockIdx.z * 128;
  const int tid = threadIdx.x, wave = tid >> 6, lane = tid & 63;
  const int q = lane >> 4, col = lane & 15;
  const int mw  = m0 + (wave & 1) * 32;
  const int c0w = c0b + (wave >> 1) * 64;

  const unsigned short* Fb = Ft + (size_t)b*Nn*K;
  const unsigned short* Hb = H  + (size_t)b*Cc*Nn;
  const float*          Zb = Z2 + (size_t)b*Nn;

  short8 gf0 = *(const short8*)(Gt + (size_t)(b*Nn + mw      + col)*K + q*8);
  short8 gf1 = *(const short8*)(Gt + (size_t)(b*Nn + mw + 16 + col)*K + q*8);

  unsigned short* Pw = &Ps[wave][0];
  const f32x4 zero = {0.f,0.f,0.f,0.f};
  f32x4 acc[2][4];
#pragma unroll
  for (int j = 0; j < 2; ++j)
#pragma unroll
    for (int i = 0; i < 4; ++i) acc[j][i] = zero;

  Gen A, B;
  auto loadGen = [&](Gen& G, int nt) {
    G.af0 = *(const short8*)(Fb + (size_t)(nt      + col)*K + q*8);
    G.af1 = *(const short8*)(Fb + (size_t)(nt + 16 + col)*K + q*8);
#pragma unroll
    for (int i = 0; i < 4; ++i)
      G.hf[i] = *(const short8*)(Hb + (size_t)(c0w + i*16 + col)*Nn + nt + q*8);
  };
  auto step = [&](int nt, Gen& CUR, Gen& NXT) {
    loadGen(NXT, (nt + 32) & (Nn - 1));
    float4 z0 = *(const float4*)(Zb + nt + q*4);
    float4 z1 = *(const float4*)(Zb + nt + 16 + q*4);
    f32x4 s00 = MF(CUR.af0, gf0, zero);
    f32x4 s01 = MF(CUR.af0, gf1, zero);
    f32x4 s10 = MF(CUR.af1, gf0, zero);
    f32x4 s11 = MF(CUR.af1, gf1, zero);
    uint2 w00 = { pack2(ex2(s00[0]-z0.x), ex2(s00[1]-z0.y)),
                  pack2(ex2(s00[2]-z0.z), ex2(s00[3]-z0.w)) };
    uint2 w01 = { pack2(ex2(s01[0]-z0.x), ex2(s01[1]-z0.y)),
                  pack2(ex2(s01[2]-z0.z), ex2(s01[3]-z0.w)) };
    uint2 w10 = { pack2(ex2(s10[0]-z1.x), ex2(s10[1]-z1.y)),
                  pack2(ex2(s10[2]-z1.z), ex2(s10[3]-z1.w)) };
    uint2 w11 = { pack2(ex2(s11[0]-z1.x), ex2(s11[1]-z1.y)),
                  pack2(ex2(s11[2]-z1.z), ex2(s11[3]-z1.w)) };
    *(uint2*)&Pw[(     col)*40      + q*4] = w00;
    *(uint2*)&Pw[(16 + col)*40      + q*4] = w01;
    *(uint2*)&Pw[(     col)*40 + 16 + q*4] = w10;
    *(uint2*)&Pw[(16 + col)*40 + 16 + q*4] = w11;
    short8 pf0 = *(const short8*)&Pw[(     col)*40 + q*8];
    short8 pf1 = *(const short8*)&Pw[(16 + col)*40 + q*8];
#pragma unroll
    for (int i = 0; i < 4; ++i) {
      acc[0][i] = MF(CUR.hf[i], pf0, acc[0][i]);
      acc[1][i] = MF(CUR.hf[i], pf1, acc[1][i]);
    }
  };

  loadGen(A, 0);
  for (int t = 0; t < 128; t += 2) {
    step(t*32,      A, B);
    step(t*32 + 32, B, A);
  }

  const float gm = gamma[0];
#pragma unroll
  for (int mj = 0; mj < 2; ++mj) {
    const int m = mw + mj*16 + col;
#pragma unroll
    for (int i = 0; i < 4; ++i) {
#pragma unroll
      for (int r = 0; r < 4; ++r) {
        int c = c0w + i*16 + q*4 + r;
        size_t idx = ((size_t)(b*Cc + c))*Nn + m;
        dst[idx] = fmaf(gm, acc[mj][i][r], x[idx]);
      }
    }
  }
}

// ===========================================================================
extern "C" void kernel_launch(void* const* d_in, const int* in_sizes, int n_in,
                              void* d_out, int out_size, void* d_ws, size_t ws_size,
                              hipStream_t stream) {
  (void)in_sizes; (void)n_in; (void)out_size;
  const float* x     = (const float*)d_in[0];
  const float* Wf    = (const float*)d_in[1];
  const float* bf    = (const float*)d_in[2];
  const float* Wg    = (const float*)d_in[3];
  const float* bg    = (const float*)d_in[4];
  const float* Wh    = (const float*)d_in[5];
  const float* bh    = (const float*)d_in[6];
  const float* gamma = (const float*)d_in[7];
  float* out = (float*)d_out;

  unsigned short* Ft   = (unsigned short*)d_ws;                // 524288 el
  unsigned short* Gt   = Ft   + (size_t)Bb*Nn*K;               // 524288 el
  unsigned short* xT   = Gt   + (size_t)Bb*Nn*K;               // 4194304 el
  unsigned short* H    = xT   + (size_t)Bb*Nn*Cc;              // 4194304 el
  unsigned short* Whb  = H    + (size_t)Bb*Cc*Nn;              // 65536 el
  unsigned short* Wfgb = Whb  + (size_t)Cc*Cc;                 // 16384 el
  float*          L    = (float*)(Wfgb + 64*Cc);               // 16384 f
  float*          Z2   = L  + (size_t)Bb*Nn;                   // 16384 f
  float*          Lp   = Z2 + (size_t)Bb*Nn;                   // 32768 f
  unsigned short* Et   = (unsigned short*)(Lp + 2*(size_t)Bb*Nn);  // 128 MB

  const size_t baseEnd = 19038208ull + 65536ull*4;             // 19300352
  const size_t needE   = baseEnd + (size_t)Bb*Nn*Nn*2;         // ~153.5 MB

  castW   <<<dim3(Cc*Cc/1024), 256, 0, stream>>>(Wh, Whb);
  castFG  <<<dim3(64*Cc/1024), 256, 0, stream>>>(Wf, Wg, Wfgb);
  trans_k <<<dim3(Nn/64, Cc/64, Bb), 256, 0, stream>>>(x, xT, out);
  proj_fgM<<<dim3(Nn/64, Bb), 256, 0, stream>>>(xT, Wfgb, bf, bg, Ft, Gt);

  if (ws_size >= needE) {
    pass1    <<<dim3(Nn/64, 2, Bb), 512, 0, stream>>>(Ft, Gt, Et, Lp);
    sumL     <<<dim3(Bb*Nn/256), 256, 0, stream>>>(Lp, L);
    proj_hT  <<<dim3(Nn/64, Cc/64, Bb), 256, 0, stream>>>(xT, Whb, bh, L, gamma, H);
    out_gemm4<<<dim3(512), 256, 0, stream>>>(H, Et, out);
  } else {
    proj_h  <<<dim3(Nn/64, Cc/64, Bb), 256, 0, stream>>>(xT, Whb, bh, H);
    stats_k <<<dim3(Nn/32, 2*Bb), 256, 0, stream>>>(Ft, Gt, Lp);
    zcomb   <<<dim3(Bb*Nn/256), 256, 0, stream>>>(Lp, Z2);
    out_k   <<<dim3(Nn/64, Bb, 2), 256, 0, stream>>>(Ft, Gt, H, Z2, x, gamma, out);
  }
}